// Round 1
// baseline (651.041 us; speedup 1.0000x reference)
//
#include <hip/hip_runtime.h>
#include <hip/hip_bf16.h>
#include <math.h>

// ---------------------------------------------------------------------------
// Problem constants (verified against in_sizes at runtime where it matters)
//   N = 65536 nodes, E = 524288 edges, HID = 128, 128 graphs x 512 nodes
// ---------------------------------------------------------------------------

// ============================ GEMM: [n,128] @ [128,128] =====================
// BM=64 rows/block, full N=128, BK=32. 256 threads, 8x4 micro-tile per thread.
// Epilogue: out = (acc + bias) * rowscale   (bias/rowscale nullable)
__global__ __launch_bounds__(256) void gemm128(
    const float* __restrict__ A, const float* __restrict__ W,
    const float* __restrict__ bias, const float* __restrict__ rowscale,
    float* __restrict__ out, int n)
{
    __shared__ float As[32 * 72];   // [k][m], row stride 72 (conflict-free transpose store)
    __shared__ float Ws[32 * 132];  // [k][c], row stride 132 (16B-aligned rows)
    const int tid  = threadIdx.x;
    const int rb   = blockIdx.x * 64;
    const int col4 = tid & 31;   // 4 cols starting at col4*4
    const int rowg = tid >> 5;   // 8 rows starting at rowg*8

    float acc[8][4];
#pragma unroll
    for (int i = 0; i < 8; i++)
#pragma unroll
        for (int j = 0; j < 4; j++) acc[i][j] = 0.f;

    for (int k0 = 0; k0 < 128; k0 += 32) {
        // stage A tile (64x32) transposed into As[k][m]
#pragma unroll
        for (int t = 0; t < 2; t++) {
            int s = tid + t * 256;       // 0..511
            int m = s >> 3, kq = s & 7;  // m: row 0..63, kq: float4 idx along k
            const float4 av = *(const float4*)&A[(size_t)(rb + m) * 128 + k0 + kq * 4];
            As[(kq * 4 + 0) * 72 + m] = av.x;
            As[(kq * 4 + 1) * 72 + m] = av.y;
            As[(kq * 4 + 2) * 72 + m] = av.z;
            As[(kq * 4 + 3) * 72 + m] = av.w;
        }
        // stage W tile (32x128) straight copy
#pragma unroll
        for (int t = 0; t < 4; t++) {
            int s = tid + t * 256;        // 0..1023
            int kk = s >> 5, cq = s & 31;
            *(float4*)&Ws[kk * 132 + cq * 4] =
                *(const float4*)&W[(size_t)(k0 + kk) * 128 + cq * 4];
        }
        __syncthreads();
#pragma unroll
        for (int kk = 0; kk < 32; kk++) {
            float4 a0 = *(const float4*)&As[kk * 72 + rowg * 8];
            float4 a1 = *(const float4*)&As[kk * 72 + rowg * 8 + 4];
            float4 b  = *(const float4*)&Ws[kk * 132 + col4 * 4];
            float av[8] = {a0.x, a0.y, a0.z, a0.w, a1.x, a1.y, a1.z, a1.w};
            float bv[4] = {b.x, b.y, b.z, b.w};
#pragma unroll
            for (int i = 0; i < 8; i++)
#pragma unroll
                for (int j = 0; j < 4; j++) acc[i][j] += av[i] * bv[j];
        }
        __syncthreads();
    }

    float4 bb = make_float4(0.f, 0.f, 0.f, 0.f);
    if (bias) bb = *(const float4*)&bias[col4 * 4];
#pragma unroll
    for (int i = 0; i < 8; i++) {
        int row  = rb + rowg * 8 + i;
        float sc = rowscale ? rowscale[row] : 1.f;
        float4 o;
        o.x = (acc[i][0] + bb.x) * sc;
        o.y = (acc[i][1] + bb.y) * sc;
        o.z = (acc[i][2] + bb.z) * sc;
        o.w = (acc[i][3] + bb.w) * sc;
        *(float4*)&out[(size_t)row * 128 + col4 * 4] = o;
    }
}

// ============================ Degree / CSR build ============================
__global__ void count_edges(const int* __restrict__ dst, int* __restrict__ cnt, int E)
{
    int e = blockIdx.x * blockDim.x + threadIdx.x;
    if (e < E) atomicAdd(&cnt[dst[e]], 1);
}

__global__ void dinv_k(const int* __restrict__ cnt, float* __restrict__ dinv, int n)
{
    int i = blockIdx.x * blockDim.x + threadIdx.x;
    if (i < n) dinv[i] = rsqrtf((float)(cnt[i] + 1));  // +1 self loop, deg >= 1
}

// hierarchical exclusive scan of cnt[n] -> offs[n] (n = 256*256)
__global__ void scan1(const int* __restrict__ cnt, int* __restrict__ offs,
                      int* __restrict__ bsum)
{
    __shared__ int tmp[256];
    int t = threadIdx.x;
    int i = blockIdx.x * 256 + t;
    int v = cnt[i];
    tmp[t] = v;
    __syncthreads();
    for (int o = 1; o < 256; o <<= 1) {
        int add = (t >= o) ? tmp[t - o] : 0;
        __syncthreads();
        tmp[t] += add;
        __syncthreads();
    }
    offs[i] = tmp[t] - v;  // exclusive within block
    if (t == 255) bsum[blockIdx.x] = tmp[255];
}

__global__ void scan2(const int* __restrict__ bsum, int* __restrict__ boff)
{
    __shared__ int tmp[256];
    int t = threadIdx.x;
    int v = bsum[t];
    tmp[t] = v;
    __syncthreads();
    for (int o = 1; o < 256; o <<= 1) {
        int add = (t >= o) ? tmp[t - o] : 0;
        __syncthreads();
        tmp[t] += add;
        __syncthreads();
    }
    boff[t] = tmp[t] - v;
}

__global__ void scan3(int* __restrict__ offs, const int* __restrict__ boff,
                      int* __restrict__ cursor, int n, int E)
{
    int i = blockIdx.x * 256 + threadIdx.x;
    int v = offs[i] + boff[blockIdx.x];
    offs[i]   = v;
    cursor[i] = v;
    if (i == 0) offs[n] = E;
}

__global__ void scatter_edges(const int* __restrict__ src, const int* __restrict__ dst,
                              int* __restrict__ cursor, int* __restrict__ csr, int E)
{
    int e = blockIdx.x * blockDim.x + threadIdx.x;
    if (e < E) {
        int d   = dst[e];
        int pos = atomicAdd(&cursor[d], 1);
        csr[pos] = src[e];
    }
}

// ============================ Aggregation ===================================
// h_out[i][c] = relu( (hs[i][c] + sum_{e in in(i)} hs[csr[e]][c]) * dinv[i] + b[c] )
// 2 nodes per 256-thread block; 128 threads (2 waves) per node, c = lane dim.
__global__ void aggregate(const float* __restrict__ hs, const int* __restrict__ csr,
                          const int* __restrict__ offs, const float* __restrict__ dinv,
                          const float* __restrict__ bias, float* __restrict__ hout, int n)
{
    int node = blockIdx.x * 2 + (threadIdx.x >> 7);
    int c    = threadIdx.x & 127;
    if (node >= n) return;
    float s = hs[(size_t)node * 128 + c];  // self loop
    int e0 = offs[node], e1 = offs[node + 1];
    for (int e = e0; e < e1; e++) {
        int sidx = csr[e];
        s += hs[(size_t)sidx * 128 + c];
    }
    float v = s * dinv[node] + bias[c];
    hout[(size_t)node * 128 + c] = fmaxf(v, 0.f);
}

// ============================ Scores ========================================
// score[i] = dot(h[i], p) / ||p||.  One wave per node, 4 nodes per block.
__global__ void scores_k(const float* __restrict__ h, const float* __restrict__ p,
                         float* __restrict__ scores, int n)
{
    int wave = threadIdx.x >> 6;
    int lane = threadIdx.x & 63;
    int node = blockIdx.x * 4 + wave;
    float p0 = p[lane], p1 = p[lane + 64];
    float nrm = p0 * p0 + p1 * p1;
#pragma unroll
    for (int o = 32; o > 0; o >>= 1) nrm += __shfl_xor(nrm, o, 64);
    float rn = rsqrtf(nrm);
    float v = h[(size_t)node * 128 + lane] * p0 + h[(size_t)node * 128 + 64 + lane] * p1;
#pragma unroll
    for (int o = 32; o > 0; o >>= 1) v += __shfl_xor(v, o, 64);
    if (lane == 0) scores[node] = v * rn;
}

// ============================ TopK pool (k=256 of 512) ======================
__global__ __launch_bounds__(512) void topk_pool(
    const float* __restrict__ scores, const float* __restrict__ h,
    float* __restrict__ pooled)
{
    __shared__ float s[512];
    __shared__ float w[512];
    __shared__ float red[512];
    int g = blockIdx.x;
    int i = threadIdx.x;
    s[i] = scores[g * 512 + i];
    __syncthreads();
    float si = s[i];
    int rank = 0;
    for (int j = 0; j < 512; j++) {
        float sj = s[j];
        rank += (sj > si) || (sj == si && j < i);
    }
    w[i] = (rank < 256) ? tanhf(si) * (1.f / 256.f) : 0.f;
    __syncthreads();
    int c   = i & 127;
    int grp = i >> 7;  // 4 groups
    float acc = 0.f;
    for (int idx = grp; idx < 512; idx += 4) {
        acc += w[idx] * h[((size_t)g * 512 + idx) * 128 + c];
    }
    red[i] = acc;
    __syncthreads();
    if (i < 128) pooled[g * 128 + i] = red[i] + red[i + 128] + red[i + 256] + red[i + 384];
}

// ============================ MLP head ======================================
__global__ __launch_bounds__(128) void mlp_head(
    const float* __restrict__ pooled,
    const float* __restrict__ fc1W, const float* __restrict__ fc1b,
    const float* __restrict__ fc2W, const float* __restrict__ fc2b,
    const float* __restrict__ fc3W, const float* __restrict__ fc3b,
    float* __restrict__ out)
{
    __shared__ float pld[128];
    __shared__ float z1[128];
    __shared__ float z2[64];
    int g = blockIdx.x, j = threadIdx.x;
    pld[j] = pooled[g * 128 + j];
    __syncthreads();
    float a = fc1b[j];
    for (int k = 0; k < 128; k++) a += pld[k] * fc1W[k * 128 + j];
    z1[j] = fmaxf(a, 0.f);
    __syncthreads();
    if (j < 64) {
        float b = fc2b[j];
        for (int k = 0; k < 128; k++) b += z1[k] * fc2W[k * 64 + j];
        z2[j] = fmaxf(b, 0.f);
    }
    __syncthreads();
    if (j < 10) {
        float o = fc3b[j];
        for (int k = 0; k < 64; k++) o += z2[k] * fc3W[k * 10 + j];
        out[g * 10 + j] = o;
    }
}

// ============================ Launcher ======================================
extern "C" void kernel_launch(void* const* d_in, const int* in_sizes, int n_in,
                              void* d_out, int out_size, void* d_ws, size_t ws_size,
                              hipStream_t stream)
{
    const float* x     = (const float*)d_in[0];
    const int*   eidx  = (const int*)d_in[1];
    // d_in[2] = batch (unused: uniform 512 nodes/graph, contiguous)
    const float* embW  = (const float*)d_in[3];
    const float* embb  = (const float*)d_in[4];
    const float* gcnW  = (const float*)d_in[5];
    const float* gcnb  = (const float*)d_in[6];
    const float* poolp = (const float*)d_in[7];
    const float* fc1W  = (const float*)d_in[8];
    const float* fc1b  = (const float*)d_in[9];
    const float* fc2W  = (const float*)d_in[10];
    const float* fc2b  = (const float*)d_in[11];
    const float* fc3W  = (const float*)d_in[12];
    const float* fc3b  = (const float*)d_in[13];
    float* out = (float*)d_out;

    const int n = in_sizes[0] / 128;   // 65536
    const int E = in_sizes[1] / 2;     // 524288
    const int G = n / 512;             // 128

    const int* src = eidx;
    const int* dst = eidx + E;

    // ---- workspace carve (aligned to 256B) ----
    char* ws = (char*)d_ws;
    size_t off = 0;
    auto carve = [&](size_t bytes) {
        void* p = ws + off;
        off += (bytes + 255) & ~(size_t)255;
        return p;
    };
    float* h      = (float*)carve((size_t)n * 128 * 4);
    float* hs     = (float*)carve((size_t)n * 128 * 4);
    float* dinv   = (float*)carve((size_t)n * 4);
    int*   cnt    = (int*)carve((size_t)n * 4);
    int*   offs   = (int*)carve((size_t)(n + 1) * 4);
    int*   cursor = (int*)carve((size_t)n * 4);
    int*   bsum   = (int*)carve(256 * 4);
    int*   boff   = (int*)carve(256 * 4);
    int*   csr    = (int*)carve((size_t)E * 4);
    float* scores = (float*)carve((size_t)n * 4);
    float* pooled = (float*)carve((size_t)G * 128 * 4);
    (void)ws_size;

    // ---- degree + CSR build (reused across all 3 layers) ----
    hipMemsetAsync(cnt, 0, (size_t)n * 4, stream);
    count_edges<<<E / 256, 256, 0, stream>>>(dst, cnt, E);
    dinv_k<<<n / 256, 256, 0, stream>>>(cnt, dinv, n);
    scan1<<<n / 256, 256, 0, stream>>>(cnt, offs, bsum);
    scan2<<<1, 256, 0, stream>>>(bsum, boff);
    scan3<<<n / 256, 256, 0, stream>>>(offs, boff, cursor, n, E);
    scatter_edges<<<E / 256, 256, 0, stream>>>(src, dst, cursor, csr, E);

    // ---- embedding ----
    gemm128<<<n / 64, 256, 0, stream>>>(x, embW, embb, nullptr, h, n);

    // ---- 3 GCN layers ----
    for (int l = 0; l < 3; l++) {
        gemm128<<<n / 64, 256, 0, stream>>>(h, gcnW + (size_t)l * 128 * 128,
                                            nullptr, dinv, hs, n);
        aggregate<<<n / 2, 256, 0, stream>>>(hs, csr, offs, dinv,
                                             gcnb + (size_t)l * 128, h, n);
    }

    // ---- scores + topk pool + MLP ----
    scores_k<<<n / 4, 256, 0, stream>>>(h, poolp, scores, n);
    topk_pool<<<G, 512, 0, stream>>>(scores, h, pooled);
    mlp_head<<<G, 128, 0, stream>>>(pooled, fc1W, fc1b, fc2W, fc2b, fc3W, fc3b, out);
}

// Round 2
// 459.141 us; speedup vs baseline: 1.4180x; 1.4180x over previous
//
#include <hip/hip_runtime.h>
#include <hip/hip_bf16.h>
#include <math.h>

// N = 65536 nodes, E = 524288 edges, HID = 128, 128 graphs x 512 nodes
// fp32 throughout: output absmax threshold ~1e-7 forbids bf16 MFMA.

static __device__ __forceinline__ float4 f4add(float4 a, float4 b) {
    return make_float4(a.x + b.x, a.y + b.y, a.z + b.z, a.w + b.w);
}
static __device__ __forceinline__ float4 f4fma(float s, float4 a, float4 acc) {
    return make_float4(fmaf(s, a.x, acc.x), fmaf(s, a.y, acc.y),
                       fmaf(s, a.z, acc.z), fmaf(s, a.w, acc.w));
}

// ============================ GEMM: [n,128] @ [128,128] =====================
// BM=128 rows/block, full N=128, BK=32. 256 threads, 8x8 micro-tile.
// LDS layout swizzle: word w -> w + (w>>5)*4 within a row (stride 140) so
// 8-float-stride b128 reads hit 2-way bank aliasing only (free per m136).
// Epilogue: out = (acc + bias) * rowscale   (bias/rowscale nullable)
#define LSTRIDE 140
__global__ __launch_bounds__(256) void gemm128(
    const float* __restrict__ A, const float* __restrict__ W,
    const float* __restrict__ bias, const float* __restrict__ rowscale,
    float* __restrict__ out, int n)
{
    __shared__ float As[32 * LSTRIDE];  // [k][m'] transposed + swizzled
    __shared__ float Ws[32 * LSTRIDE];  // [k][c'] swizzled
    const int tid  = threadIdx.x;
    const int rb   = blockIdx.x * 128;
    const int colg = (tid & 15) * 8;   // 8 cols
    const int rowg = (tid >> 4) * 8;   // 8 rows
    const int rowgp = rowg + ((rowg >> 5) << 2);
    const int colgp = colg + ((colg >> 5) << 2);

    float acc[8][8];
#pragma unroll
    for (int i = 0; i < 8; i++)
#pragma unroll
        for (int j = 0; j < 8; j++) acc[i][j] = 0.f;

#pragma unroll 1
    for (int k0 = 0; k0 < 128; k0 += 32) {
        // stage A tile (128 rows x 32 k) transposed into As[k][m']
#pragma unroll
        for (int t = 0; t < 4; t++) {
            int s = tid + t * 256;       // 0..1023
            int m = s >> 3, kq = s & 7;  // row, float4-idx along k
            const float4 av = *(const float4*)&A[(size_t)(rb + m) * 128 + k0 + kq * 4];
            int mp = m + ((m >> 5) << 2);
            As[(kq * 4 + 0) * LSTRIDE + mp] = av.x;
            As[(kq * 4 + 1) * LSTRIDE + mp] = av.y;
            As[(kq * 4 + 2) * LSTRIDE + mp] = av.z;
            As[(kq * 4 + 3) * LSTRIDE + mp] = av.w;
        }
        // stage W tile (32 k x 128 c) straight, swizzled cols
#pragma unroll
        for (int t = 0; t < 4; t++) {
            int s = tid + t * 256;           // 0..1023
            int kk = s >> 5, cq = (s & 31) * 4;
            const float4 wv = *(const float4*)&W[(size_t)(k0 + kk) * 128 + cq];
            int cp = cq + ((cq >> 5) << 2);
            *(float4*)&Ws[kk * LSTRIDE + cp] = wv;
        }
        __syncthreads();
#pragma unroll 16
        for (int kk = 0; kk < 32; kk++) {
            float4 a0 = *(const float4*)&As[kk * LSTRIDE + rowgp];
            float4 a1 = *(const float4*)&As[kk * LSTRIDE + rowgp + 4];
            float4 b0 = *(const float4*)&Ws[kk * LSTRIDE + colgp];
            float4 b1 = *(const float4*)&Ws[kk * LSTRIDE + colgp + 4];
            float av[8] = {a0.x, a0.y, a0.z, a0.w, a1.x, a1.y, a1.z, a1.w};
            float bv[8] = {b0.x, b0.y, b0.z, b0.w, b1.x, b1.y, b1.z, b1.w};
#pragma unroll
            for (int i = 0; i < 8; i++)
#pragma unroll
                for (int j = 0; j < 8; j++) acc[i][j] = fmaf(av[i], bv[j], acc[i][j]);
        }
        __syncthreads();
    }

    float4 bb0 = make_float4(0.f, 0.f, 0.f, 0.f), bb1 = bb0;
    if (bias) {
        bb0 = *(const float4*)&bias[colg];
        bb1 = *(const float4*)&bias[colg + 4];
    }
#pragma unroll
    for (int i = 0; i < 8; i++) {
        int row  = rb + rowg + i;
        float sc = rowscale ? rowscale[row] : 1.f;
        float4 o0, o1;
        o0.x = (acc[i][0] + bb0.x) * sc;  o0.y = (acc[i][1] + bb0.y) * sc;
        o0.z = (acc[i][2] + bb0.z) * sc;  o0.w = (acc[i][3] + bb0.w) * sc;
        o1.x = (acc[i][4] + bb1.x) * sc;  o1.y = (acc[i][5] + bb1.y) * sc;
        o1.z = (acc[i][6] + bb1.z) * sc;  o1.w = (acc[i][7] + bb1.w) * sc;
        *(float4*)&out[(size_t)row * 128 + colg]     = o0;
        *(float4*)&out[(size_t)row * 128 + colg + 4] = o1;
    }
}

// ============================ Degree / CSR build ============================
__global__ void count_edges(const int* __restrict__ dst, int* __restrict__ cnt, int E)
{
    int e = blockIdx.x * blockDim.x + threadIdx.x;
    if (e < E) atomicAdd(&cnt[dst[e]], 1);
}

__global__ void dinv_k(const int* __restrict__ cnt, float* __restrict__ dinv, int n)
{
    int i = blockIdx.x * blockDim.x + threadIdx.x;
    if (i < n) dinv[i] = rsqrtf((float)(cnt[i] + 1));  // +1 self loop
}

__global__ void scan1(const int* __restrict__ cnt, int* __restrict__ offs,
                      int* __restrict__ bsum)
{
    __shared__ int tmp[256];
    int t = threadIdx.x;
    int i = blockIdx.x * 256 + t;
    int v = cnt[i];
    tmp[t] = v;
    __syncthreads();
    for (int o = 1; o < 256; o <<= 1) {
        int add = (t >= o) ? tmp[t - o] : 0;
        __syncthreads();
        tmp[t] += add;
        __syncthreads();
    }
    offs[i] = tmp[t] - v;
    if (t == 255) bsum[blockIdx.x] = tmp[255];
}

__global__ void scan2(const int* __restrict__ bsum, int* __restrict__ boff)
{
    __shared__ int tmp[256];
    int t = threadIdx.x;
    int v = bsum[t];
    tmp[t] = v;
    __syncthreads();
    for (int o = 1; o < 256; o <<= 1) {
        int add = (t >= o) ? tmp[t - o] : 0;
        __syncthreads();
        tmp[t] += add;
        __syncthreads();
    }
    boff[t] = tmp[t] - v;
}

__global__ void scan3(int* __restrict__ offs, const int* __restrict__ boff,
                      int* __restrict__ cursor, int n, int E)
{
    int i = blockIdx.x * 256 + threadIdx.x;
    int v = offs[i] + boff[blockIdx.x];
    offs[i]   = v;
    cursor[i] = v;
    if (i == 0) offs[n] = E;
}

__global__ void scatter_edges(const int* __restrict__ src, const int* __restrict__ dst,
                              int* __restrict__ cursor, int* __restrict__ csr, int E)
{
    int e = blockIdx.x * blockDim.x + threadIdx.x;
    if (e < E) {
        int d   = dst[e];
        int pos = atomicAdd(&cursor[d], 1);
        csr[pos] = src[e];
    }
}

// ============================ Aggregation ===================================
// h_out[i] = relu((hs[i] + sum_{src in in(i)} hs[src]) * dinv[i] + b)
// 32 lanes per node (float4/lane), 8 nodes per 256-thread block.
// 4 neighbor rows in flight (independent accumulators) for memory-level ||ism.
// Optionally fuses pooling-score: score[i] = dot(h_out[i], p)/||p||.
__global__ __launch_bounds__(256) void aggregate(
    const float* __restrict__ hs, const int* __restrict__ csr,
    const int* __restrict__ offs, const float* __restrict__ dinv,
    const float* __restrict__ bias, float* __restrict__ hout,
    const float* __restrict__ pool_p, float* __restrict__ scores, int n)
{
    const int grp  = threadIdx.x >> 5;
    const int lane = threadIdx.x & 31;
    const int node = blockIdx.x * 8 + grp;
    const float4* __restrict__ hv = (const float4*)hs;

    float4 a0 = hv[(size_t)node * 32 + lane];  // self loop
    float4 a1 = make_float4(0.f, 0.f, 0.f, 0.f);
    float4 a2 = a1, a3 = a1;

    const int e1 = offs[node + 1];
    int e = offs[node];
    for (; e + 4 <= e1; e += 4) {
        int i0 = csr[e + 0], i1 = csr[e + 1], i2 = csr[e + 2], i3 = csr[e + 3];
        float4 r0 = hv[(size_t)i0 * 32 + lane];
        float4 r1 = hv[(size_t)i1 * 32 + lane];
        float4 r2 = hv[(size_t)i2 * 32 + lane];
        float4 r3 = hv[(size_t)i3 * 32 + lane];
        a0 = f4add(a0, r0); a1 = f4add(a1, r1);
        a2 = f4add(a2, r2); a3 = f4add(a3, r3);
    }
    for (; e < e1; e++) {
        int i0 = csr[e];
        a1 = f4add(a1, hv[(size_t)i0 * 32 + lane]);
    }
    float4 s = f4add(f4add(a0, a1), f4add(a2, a3));
    float dv = dinv[node];
    float4 bb = ((const float4*)bias)[lane];
    float4 o;
    o.x = fmaxf(fmaf(s.x, dv, bb.x), 0.f);
    o.y = fmaxf(fmaf(s.y, dv, bb.y), 0.f);
    o.z = fmaxf(fmaf(s.z, dv, bb.z), 0.f);
    o.w = fmaxf(fmaf(s.w, dv, bb.w), 0.f);
    ((float4*)hout)[(size_t)node * 32 + lane] = o;

    if (scores) {  // wave-uniform branch
        float4 pv = ((const float4*)pool_p)[lane];
        float d  = o.x * pv.x + o.y * pv.y + o.z * pv.z + o.w * pv.w;
        float nn = pv.x * pv.x + pv.y * pv.y + pv.z * pv.z + pv.w * pv.w;
#pragma unroll
        for (int off = 16; off > 0; off >>= 1) {
            d  += __shfl_xor(d, off);
            nn += __shfl_xor(nn, off);
        }
        if (lane == 0) scores[node] = d * rsqrtf(nn);
    }
}

// ============================ TopK pool (k=256 of 512) ======================
// Rank by O(512^2) LDS comparison, compact selected indices, gather only the
// 256 selected rows (float4 lanes), tree-reduce the weighted mean.
__global__ __launch_bounds__(512) void topk_pool(
    const float* __restrict__ scores, const float* __restrict__ h,
    float* __restrict__ pooled)
{
    __shared__ float s[512];
    __shared__ int   sel[256];
    __shared__ float w[256];
    __shared__ float4 red[512];
    const int g = blockIdx.x;
    const int i = threadIdx.x;
    s[i] = scores[g * 512 + i];
    __syncthreads();
    float si = s[i];
    int rank = 0;
    for (int j = 0; j < 512; j++) {
        float sj = s[j];
        rank += (sj > si) || (sj == si && j < i);
    }
    if (rank < 256) {
        sel[rank] = i;
        w[rank]   = tanhf(si) * (1.f / 256.f);
    }
    __syncthreads();
    const int c   = (i & 31) * 4;  // float4 col
    const int grp = i >> 5;        // 16 groups
    float4 acc = make_float4(0.f, 0.f, 0.f, 0.f);
    for (int t = grp; t < 256; t += 16) {
        float wt  = w[t];
        int   idx = sel[t];
        float4 r = *(const float4*)&h[((size_t)g * 512 + idx) * 128 + c];
        acc = f4fma(wt, r, acc);
    }
    red[i] = acc;
    __syncthreads();
    if (i < 256) red[i] = f4add(red[i], red[i + 256]);
    __syncthreads();
    if (i < 128) red[i] = f4add(red[i], red[i + 128]);
    __syncthreads();
    if (i < 64) red[i] = f4add(red[i], red[i + 64]);
    __syncthreads();
    if (i < 32) {
        float4 v = f4add(red[i], red[i + 32]);
        *(float4*)&pooled[g * 128 + i * 4] = v;
    }
}

// ============================ MLP head ======================================
__global__ __launch_bounds__(128) void mlp_head(
    const float* __restrict__ pooled,
    const float* __restrict__ fc1W, const float* __restrict__ fc1b,
    const float* __restrict__ fc2W, const float* __restrict__ fc2b,
    const float* __restrict__ fc3W, const float* __restrict__ fc3b,
    float* __restrict__ out)
{
    __shared__ float pld[128];
    __shared__ float z1[128];
    __shared__ float z2[64];
    int g = blockIdx.x, j = threadIdx.x;
    pld[j] = pooled[g * 128 + j];
    __syncthreads();
    float a = fc1b[j];
    for (int k = 0; k < 128; k++) a += pld[k] * fc1W[k * 128 + j];
    z1[j] = fmaxf(a, 0.f);
    __syncthreads();
    if (j < 64) {
        float b = fc2b[j];
        for (int k = 0; k < 128; k++) b += z1[k] * fc2W[k * 64 + j];
        z2[j] = fmaxf(b, 0.f);
    }
    __syncthreads();
    if (j < 10) {
        float o = fc3b[j];
        for (int k = 0; k < 64; k++) o += z2[k] * fc3W[k * 10 + j];
        out[g * 10 + j] = o;
    }
}

// ============================ Launcher ======================================
extern "C" void kernel_launch(void* const* d_in, const int* in_sizes, int n_in,
                              void* d_out, int out_size, void* d_ws, size_t ws_size,
                              hipStream_t stream)
{
    const float* x     = (const float*)d_in[0];
    const int*   eidx  = (const int*)d_in[1];
    const float* embW  = (const float*)d_in[3];
    const float* embb  = (const float*)d_in[4];
    const float* gcnW  = (const float*)d_in[5];
    const float* gcnb  = (const float*)d_in[6];
    const float* poolp = (const float*)d_in[7];
    const float* fc1W  = (const float*)d_in[8];
    const float* fc1b  = (const float*)d_in[9];
    const float* fc2W  = (const float*)d_in[10];
    const float* fc2b  = (const float*)d_in[11];
    const float* fc3W  = (const float*)d_in[12];
    const float* fc3b  = (const float*)d_in[13];
    float* out = (float*)d_out;

    const int n = in_sizes[0] / 128;   // 65536
    const int E = in_sizes[1] / 2;     // 524288
    const int G = n / 512;             // 128

    const int* src = eidx;
    const int* dst = eidx + E;

    char* ws = (char*)d_ws;
    size_t off = 0;
    auto carve = [&](size_t bytes) {
        void* p = ws + off;
        off += (bytes + 255) & ~(size_t)255;
        return p;
    };
    float* h      = (float*)carve((size_t)n * 128 * 4);
    float* hs     = (float*)carve((size_t)n * 128 * 4);
    float* dinv   = (float*)carve((size_t)n * 4);
    int*   cnt    = (int*)carve((size_t)n * 4);
    int*   offs   = (int*)carve((size_t)(n + 1) * 4);
    int*   cursor = (int*)carve((size_t)n * 4);
    int*   bsum   = (int*)carve(256 * 4);
    int*   boff   = (int*)carve(256 * 4);
    int*   csr    = (int*)carve((size_t)E * 4);
    float* scores = (float*)carve((size_t)n * 4);
    float* pooled = (float*)carve((size_t)G * 128 * 4);
    (void)ws_size;

    // ---- degree + CSR build ----
    hipMemsetAsync(cnt, 0, (size_t)n * 4, stream);
    count_edges<<<E / 256, 256, 0, stream>>>(dst, cnt, E);
    dinv_k<<<n / 256, 256, 0, stream>>>(cnt, dinv, n);
    scan1<<<n / 256, 256, 0, stream>>>(cnt, offs, bsum);
    scan2<<<1, 256, 0, stream>>>(bsum, boff);
    scan3<<<n / 256, 256, 0, stream>>>(offs, boff, cursor, n, E);
    scatter_edges<<<E / 256, 256, 0, stream>>>(src, dst, cursor, csr, E);

    // ---- embedding ----
    gemm128<<<n / 128, 256, 0, stream>>>(x, embW, embb, nullptr, h, n);

    // ---- 3 GCN layers (score fused into last aggregate) ----
    for (int l = 0; l < 3; l++) {
        gemm128<<<n / 128, 256, 0, stream>>>(h, gcnW + (size_t)l * 128 * 128,
                                             nullptr, dinv, hs, n);
        aggregate<<<n / 8, 256, 0, stream>>>(
            hs, csr, offs, dinv, gcnb + (size_t)l * 128, h,
            poolp, (l == 2) ? scores : nullptr, n);
    }

    // ---- topk pool + MLP ----
    topk_pool<<<G, 512, 0, stream>>>(scores, h, pooled);
    mlp_head<<<G, 128, 0, stream>>>(pooled, fc1W, fc1b, fc2W, fc2b, fc3W, fc3b, out);
}

// Round 3
// 435.953 us; speedup vs baseline: 1.4934x; 1.0532x over previous
//
#include <hip/hip_runtime.h>
#include <hip/hip_bf16.h>
#include <math.h>

// N = 65536 nodes, E = 524288 edges, HID = 128, 128 graphs x 512 nodes
// fp32 throughout: absmax threshold ~9.8e-8 forbids bf16 MFMA.
// Embedding GEMM is folded into layer-0 weights: x@(embW@W0)+embb@W0.

static __device__ __forceinline__ float4 f4add(float4 a, float4 b) {
    return make_float4(a.x + b.x, a.y + b.y, a.z + b.z, a.w + b.w);
}
static __device__ __forceinline__ float4 f4fma(float s, float4 a, float4 acc) {
    return make_float4(fmaf(s, a.x, acc.x), fmaf(s, a.y, acc.y),
                       fmaf(s, a.z, acc.z), fmaf(s, a.w, acc.w));
}

// ================== Weight fold: [embW; embb](129x128) @ W0 ================
__global__ __launch_bounds__(128) void fold_emb(
    const float* __restrict__ embW, const float* __restrict__ embb,
    const float* __restrict__ W0, float* __restrict__ W01,
    float* __restrict__ b01)
{
    const int r = blockIdx.x;   // 0..128; r==128 -> bias row
    const int c = threadIdx.x;
    __shared__ float rs[128];
    rs[c] = (r < 128) ? embW[r * 128 + c] : embb[c];
    __syncthreads();
    float s = 0.f;
#pragma unroll 8
    for (int k = 0; k < 128; k++) s = fmaf(rs[k], W0[k * 128 + c], s);
    if (r < 128) W01[r * 128 + c] = s;
    else         b01[c] = s;
}

// ============================ GEMM: [n,128] @ [128,128] =====================
// BM=256 rows/block, full N=128, BK=32. 256 threads, 16x8 micro-tile.
// Register-prefetch of next k-chunk hides global latency behind the FMA loop.
// As stride 260 (2-way read aliasing only); Ws swizzle c->c+4*(c>>5), str 140.
// Epilogue: out = (acc + bias) * rowscale   (bias/rowscale nullable)
#define ASTRIDE 260
#define WSTRIDE 140
__global__ __launch_bounds__(256) void gemm128(
    const float* __restrict__ A, const float* __restrict__ W,
    const float* __restrict__ bias, const float* __restrict__ rowscale,
    float* __restrict__ out, int n)
{
    __shared__ float As[32 * ASTRIDE];  // [k][m] transposed
    __shared__ float Ws[32 * WSTRIDE];  // [k][c'] swizzled
    const int tid  = threadIdx.x;
    const int rb   = blockIdx.x * 256;
    const int tc   = tid & 15;
    const int tr   = tid >> 4;
    const int colg = tc * 8;
    const int cswz = colg + ((colg >> 5) << 2);
    const int rowg = tr * 16;

    // staging coords
    const int a_kq = tid & 7;    // float4 idx along k
    const int a_r0 = tid >> 3;   // row within 32-row group
    const int w_c  = (tid & 31) * 4;
    const int w_cs = w_c + ((w_c >> 5) << 2);
    const int w_k  = tid >> 5;

    float acc[16][8];
#pragma unroll
    for (int i = 0; i < 16; i++)
#pragma unroll
        for (int j = 0; j < 8; j++) acc[i][j] = 0.f;

    float4 areg[8], wreg[4];
#pragma unroll
    for (int t = 0; t < 8; t++)
        areg[t] = *(const float4*)&A[(size_t)(rb + t * 32 + a_r0) * 128 + a_kq * 4];
#pragma unroll
    for (int t = 0; t < 4; t++)
        wreg[t] = *(const float4*)&W[(size_t)(t * 8 + w_k) * 128 + w_c];

#pragma unroll 1
    for (int k0 = 0; k0 < 128; k0 += 32) {
#pragma unroll
        for (int t = 0; t < 8; t++) {
            const int m = t * 32 + a_r0;
            const float4 av = areg[t];
            As[(a_kq * 4 + 0) * ASTRIDE + m] = av.x;
            As[(a_kq * 4 + 1) * ASTRIDE + m] = av.y;
            As[(a_kq * 4 + 2) * ASTRIDE + m] = av.z;
            As[(a_kq * 4 + 3) * ASTRIDE + m] = av.w;
        }
#pragma unroll
        for (int t = 0; t < 4; t++)
            *(float4*)&Ws[(t * 8 + w_k) * WSTRIDE + w_cs] = wreg[t];
        __syncthreads();
        if (k0 < 96) {
#pragma unroll
            for (int t = 0; t < 8; t++)
                areg[t] = *(const float4*)&A[(size_t)(rb + t * 32 + a_r0) * 128 + k0 + 32 + a_kq * 4];
#pragma unroll
            for (int t = 0; t < 4; t++)
                wreg[t] = *(const float4*)&W[(size_t)(k0 + 32 + t * 8 + w_k) * 128 + w_c];
        }
#pragma unroll 8
        for (int kk = 0; kk < 32; kk++) {
            const float* ar = &As[kk * ASTRIDE + rowg];
            float4 a0 = *(const float4*)&ar[0];
            float4 a1 = *(const float4*)&ar[4];
            float4 a2 = *(const float4*)&ar[8];
            float4 a3 = *(const float4*)&ar[12];
            float4 b0 = *(const float4*)&Ws[kk * WSTRIDE + cswz];
            float4 b1 = *(const float4*)&Ws[kk * WSTRIDE + cswz + 4];
            float av[16] = {a0.x, a0.y, a0.z, a0.w, a1.x, a1.y, a1.z, a1.w,
                            a2.x, a2.y, a2.z, a2.w, a3.x, a3.y, a3.z, a3.w};
            float bv[8]  = {b0.x, b0.y, b0.z, b0.w, b1.x, b1.y, b1.z, b1.w};
#pragma unroll
            for (int i = 0; i < 16; i++)
#pragma unroll
                for (int j = 0; j < 8; j++) acc[i][j] = fmaf(av[i], bv[j], acc[i][j]);
        }
        __syncthreads();
    }

    float4 bb0 = make_float4(0.f, 0.f, 0.f, 0.f), bb1 = bb0;
    if (bias) {
        bb0 = *(const float4*)&bias[colg];
        bb1 = *(const float4*)&bias[colg + 4];
    }
#pragma unroll
    for (int i = 0; i < 16; i++) {
        const int row  = rb + rowg + i;
        const float sc = rowscale ? rowscale[row] : 1.f;
        float4 o0, o1;
        o0.x = (acc[i][0] + bb0.x) * sc;  o0.y = (acc[i][1] + bb0.y) * sc;
        o0.z = (acc[i][2] + bb0.z) * sc;  o0.w = (acc[i][3] + bb0.w) * sc;
        o1.x = (acc[i][4] + bb1.x) * sc;  o1.y = (acc[i][5] + bb1.y) * sc;
        o1.z = (acc[i][6] + bb1.z) * sc;  o1.w = (acc[i][7] + bb1.w) * sc;
        *(float4*)&out[(size_t)row * 128 + colg]     = o0;
        *(float4*)&out[(size_t)row * 128 + colg + 4] = o1;
    }
}

// ============================ Degree / CSR build ============================
__global__ void count_edges(const int* __restrict__ dst, int* __restrict__ cnt, int E)
{
    int e = blockIdx.x * blockDim.x + threadIdx.x;
    if (e < E) atomicAdd(&cnt[dst[e]], 1);
}

__global__ void dinv_k(const int* __restrict__ cnt, float* __restrict__ dinv, int n)
{
    int i = blockIdx.x * blockDim.x + threadIdx.x;
    if (i < n) dinv[i] = rsqrtf((float)(cnt[i] + 1));  // +1 self loop
}

__global__ void scan1(const int* __restrict__ cnt, int* __restrict__ offs,
                      int* __restrict__ bsum)
{
    __shared__ int tmp[256];
    int t = threadIdx.x;
    int i = blockIdx.x * 256 + t;
    int v = cnt[i];
    tmp[t] = v;
    __syncthreads();
    for (int o = 1; o < 256; o <<= 1) {
        int add = (t >= o) ? tmp[t - o] : 0;
        __syncthreads();
        tmp[t] += add;
        __syncthreads();
    }
    offs[i] = tmp[t] - v;
    if (t == 255) bsum[blockIdx.x] = tmp[255];
}

__global__ void scan2(const int* __restrict__ bsum, int* __restrict__ boff)
{
    __shared__ int tmp[256];
    int t = threadIdx.x;
    int v = bsum[t];
    tmp[t] = v;
    __syncthreads();
    for (int o = 1; o < 256; o <<= 1) {
        int add = (t >= o) ? tmp[t - o] : 0;
        __syncthreads();
        tmp[t] += add;
        __syncthreads();
    }
    boff[t] = tmp[t] - v;
}

__global__ void scan3(int* __restrict__ offs, const int* __restrict__ boff,
                      int* __restrict__ cursor, int n, int E)
{
    int i = blockIdx.x * 256 + threadIdx.x;
    int v = offs[i] + boff[blockIdx.x];
    offs[i]   = v;
    cursor[i] = v;
    if (i == 0) offs[n] = E;
}

__global__ void scatter_edges(const int* __restrict__ src, const int* __restrict__ dst,
                              int* __restrict__ cursor, int* __restrict__ csr, int E)
{
    int e = blockIdx.x * blockDim.x + threadIdx.x;
    if (e < E) {
        int d   = dst[e];
        int pos = atomicAdd(&cursor[d], 1);
        csr[pos] = src[e];
    }
}

// ============================ Aggregation ===================================
// h_out[i] = relu((hs[i] + sum_{src in in(i)} hs[src]) * dinv[i] + b)
// 32 lanes per node (float4/lane), 8 nodes per 256-thread block.
// Flat masked 16-wide gather (covers deg<=16, ~99.7% of nodes); rare serial
// fallback for deg>16. All 16 row loads issue as one in-flight group.
__global__ __launch_bounds__(256) void aggregate(
    const float* __restrict__ hs, const int* __restrict__ csr,
    const int* __restrict__ offs, const float* __restrict__ dinv,
    const float* __restrict__ bias, float* __restrict__ hout,
    const float* __restrict__ pool_p, float* __restrict__ scores, int n)
{
    const int grp  = threadIdx.x >> 5;
    const int lane = threadIdx.x & 31;
    const int node = blockIdx.x * 8 + grp;
    const float4* __restrict__ hv = (const float4*)hs;

    const int e0 = offs[node], e1 = offs[node + 1];

    int   ix[16];
    float mk[16];
#pragma unroll
    for (int j = 0; j < 16; j++) {
        const int  e  = e0 + j;
        const bool v  = e < e1;
        const int  ce = v ? e : (e1 > 0 ? e1 - 1 : 0);
        ix[j] = csr[ce];
        mk[j] = v ? 1.f : 0.f;
    }

    float4 a0 = hv[(size_t)node * 32 + lane];  // self loop
    float4 a1 = make_float4(0.f, 0.f, 0.f, 0.f);
    float4 a2 = a1, a3 = a1;

#pragma unroll
    for (int b = 0; b < 2; b++) {
        float4 r[8];
#pragma unroll
        for (int j = 0; j < 8; j++)
            r[j] = hv[(size_t)ix[b * 8 + j] * 32 + lane];
        a0 = f4fma(mk[b * 8 + 0], r[0], a0);
        a1 = f4fma(mk[b * 8 + 1], r[1], a1);
        a2 = f4fma(mk[b * 8 + 2], r[2], a2);
        a3 = f4fma(mk[b * 8 + 3], r[3], a3);
        a0 = f4fma(mk[b * 8 + 4], r[4], a0);
        a1 = f4fma(mk[b * 8 + 5], r[5], a1);
        a2 = f4fma(mk[b * 8 + 6], r[6], a2);
        a3 = f4fma(mk[b * 8 + 7], r[7], a3);
    }
    for (int e = e0 + 16; e < e1; e++) {  // rare tail (deg > 16)
        a1 = f4add(a1, hv[(size_t)csr[e] * 32 + lane]);
    }

    float4 s = f4add(f4add(a0, a1), f4add(a2, a3));
    const float dv = dinv[node];
    const float4 bb = ((const float4*)bias)[lane];
    float4 o;
    o.x = fmaxf(fmaf(s.x, dv, bb.x), 0.f);
    o.y = fmaxf(fmaf(s.y, dv, bb.y), 0.f);
    o.z = fmaxf(fmaf(s.z, dv, bb.z), 0.f);
    o.w = fmaxf(fmaf(s.w, dv, bb.w), 0.f);
    ((float4*)hout)[(size_t)node * 32 + lane] = o;

    if (scores) {  // wave-uniform branch (fused pooling score)
        float4 pv = ((const float4*)pool_p)[lane];
        float d  = o.x * pv.x + o.y * pv.y + o.z * pv.z + o.w * pv.w;
        float nn = pv.x * pv.x + pv.y * pv.y + pv.z * pv.z + pv.w * pv.w;
#pragma unroll
        for (int off = 16; off > 0; off >>= 1) {
            d  += __shfl_xor(d, off);
            nn += __shfl_xor(nn, off);
        }
        if (lane == 0) scores[node] = d * rsqrtf(nn);
    }
}

// ============================ TopK pool (k=256 of 512) ======================
__global__ __launch_bounds__(512) void topk_pool(
    const float* __restrict__ scores, const float* __restrict__ h,
    float* __restrict__ pooled)
{
    __shared__ float s[512];
    __shared__ int   sel[256];
    __shared__ float w[256];
    __shared__ float4 red[512];
    const int g = blockIdx.x;
    const int i = threadIdx.x;
    s[i] = scores[g * 512 + i];
    __syncthreads();
    float si = s[i];
    int rank = 0;
    for (int j = 0; j < 512; j++) {
        float sj = s[j];
        rank += (sj > si) || (sj == si && j < i);
    }
    if (rank < 256) {
        sel[rank] = i;
        w[rank]   = tanhf(si) * (1.f / 256.f);
    }
    __syncthreads();
    const int c   = (i & 31) * 4;
    const int grp = i >> 5;
    float4 acc = make_float4(0.f, 0.f, 0.f, 0.f);
    for (int t = grp; t < 256; t += 16) {
        float wt  = w[t];
        int   idx = sel[t];
        float4 r = *(const float4*)&h[((size_t)g * 512 + idx) * 128 + c];
        acc = f4fma(wt, r, acc);
    }
    red[i] = acc;
    __syncthreads();
    if (i < 256) red[i] = f4add(red[i], red[i + 256]);
    __syncthreads();
    if (i < 128) red[i] = f4add(red[i], red[i + 128]);
    __syncthreads();
    if (i < 64) red[i] = f4add(red[i], red[i + 64]);
    __syncthreads();
    if (i < 32) {
        float4 v = f4add(red[i], red[i + 32]);
        *(float4*)&pooled[g * 128 + i * 4] = v;
    }
}

// ============================ MLP head ======================================
__global__ __launch_bounds__(128) void mlp_head(
    const float* __restrict__ pooled,
    const float* __restrict__ fc1W, const float* __restrict__ fc1b,
    const float* __restrict__ fc2W, const float* __restrict__ fc2b,
    const float* __restrict__ fc3W, const float* __restrict__ fc3b,
    float* __restrict__ out)
{
    __shared__ float pld[128];
    __shared__ float z1[128];
    __shared__ float z2[64];
    int g = blockIdx.x, j = threadIdx.x;
    pld[j] = pooled[g * 128 + j];
    __syncthreads();
    float a = fc1b[j];
    for (int k = 0; k < 128; k++) a += pld[k] * fc1W[k * 128 + j];
    z1[j] = fmaxf(a, 0.f);
    __syncthreads();
    if (j < 64) {
        float b = fc2b[j];
        for (int k = 0; k < 128; k++) b += z1[k] * fc2W[k * 64 + j];
        z2[j] = fmaxf(b, 0.f);
    }
    __syncthreads();
    if (j < 10) {
        float o = fc3b[j];
        for (int k = 0; k < 64; k++) o += z2[k] * fc3W[k * 10 + j];
        out[g * 10 + j] = o;
    }
}

// ============================ Launcher ======================================
extern "C" void kernel_launch(void* const* d_in, const int* in_sizes, int n_in,
                              void* d_out, int out_size, void* d_ws, size_t ws_size,
                              hipStream_t stream)
{
    const float* x     = (const float*)d_in[0];
    const int*   eidx  = (const int*)d_in[1];
    const float* embW  = (const float*)d_in[3];
    const float* embb  = (const float*)d_in[4];
    const float* gcnW  = (const float*)d_in[5];
    const float* gcnb  = (const float*)d_in[6];
    const float* poolp = (const float*)d_in[7];
    const float* fc1W  = (const float*)d_in[8];
    const float* fc1b  = (const float*)d_in[9];
    const float* fc2W  = (const float*)d_in[10];
    const float* fc2b  = (const float*)d_in[11];
    const float* fc3W  = (const float*)d_in[12];
    const float* fc3b  = (const float*)d_in[13];
    float* out = (float*)d_out;

    const int n = in_sizes[0] / 128;   // 65536
    const int E = in_sizes[1] / 2;     // 524288
    const int G = n / 512;             // 128

    const int* src = eidx;
    const int* dst = eidx + E;

    char* ws = (char*)d_ws;
    size_t off = 0;
    auto carve = [&](size_t bytes) {
        void* p = ws + off;
        off += (bytes + 255) & ~(size_t)255;
        return p;
    };
    float* h      = (float*)carve((size_t)n * 128 * 4);
    float* hs     = (float*)carve((size_t)n * 128 * 4);
    float* dinv   = (float*)carve((size_t)n * 4);
    int*   cnt    = (int*)carve((size_t)n * 4);
    int*   offs   = (int*)carve((size_t)(n + 1) * 4);
    int*   cursor = (int*)carve((size_t)n * 4);
    int*   bsum   = (int*)carve(256 * 4);
    int*   boff   = (int*)carve(256 * 4);
    int*   csr    = (int*)carve((size_t)E * 4);
    float* scores = (float*)carve((size_t)n * 4);
    float* pooled = (float*)carve((size_t)G * 128 * 4);
    float* W01    = (float*)carve(128 * 128 * 4);
    float* b01    = (float*)carve(128 * 4);
    (void)ws_size;

    // ---- degree + CSR build ----
    hipMemsetAsync(cnt, 0, (size_t)n * 4, stream);
    count_edges<<<E / 256, 256, 0, stream>>>(dst, cnt, E);
    dinv_k<<<n / 256, 256, 0, stream>>>(cnt, dinv, n);
    scan1<<<n / 256, 256, 0, stream>>>(cnt, offs, bsum);
    scan2<<<1, 256, 0, stream>>>(bsum, boff);
    scan3<<<n / 256, 256, 0, stream>>>(offs, boff, cursor, n, E);
    scatter_edges<<<E / 256, 256, 0, stream>>>(src, dst, cursor, csr, E);

    // ---- embedding folded into layer-0 weight ----
    fold_emb<<<129, 128, 0, stream>>>(embW, embb, gcnW, W01, b01);

    // ---- layer 0 (folded) ----
    gemm128<<<n / 256, 256, 0, stream>>>(x, W01, b01, dinv, hs, n);
    aggregate<<<n / 8, 256, 0, stream>>>(hs, csr, offs, dinv, gcnb, h,
                                         poolp, nullptr, n);

    // ---- layers 1,2 (score fused into last aggregate) ----
    for (int l = 1; l < 3; l++) {
        gemm128<<<n / 256, 256, 0, stream>>>(h, gcnW + (size_t)l * 128 * 128,
                                             nullptr, dinv, hs, n);
        aggregate<<<n / 8, 256, 0, stream>>>(
            hs, csr, offs, dinv, gcnb + (size_t)l * 128, h,
            poolp, (l == 2) ? scores : nullptr, n);
    }

    // ---- topk pool + MLP ----
    topk_pool<<<G, 512, 0, stream>>>(scores, h, pooled);
    mlp_head<<<G, 128, 0, stream>>>(pooled, fc1W, fc1b, fc2W, fc2b, fc3W, fc3b, out);
}

// Round 5
// 430.461 us; speedup vs baseline: 1.5124x; 1.0128x over previous
//
#include <hip/hip_runtime.h>
#include <hip/hip_bf16.h>
#include <math.h>

// N = 65536 nodes, E = 524288 edges, HID = 128, 128 graphs x 512 nodes
// fp32 throughout: absmax threshold ~9.8e-8 forbids bf16 MFMA.
// Embedding GEMM folded into layer-0 weights: x@(embW@W0)+embb@W0.

static __device__ __forceinline__ float4 f4add(float4 a, float4 b) {
    return make_float4(a.x + b.x, a.y + b.y, a.z + b.z, a.w + b.w);
}
static __device__ __forceinline__ float4 f4fma(float s, float4 a, float4 acc) {
    return make_float4(fmaf(s, a.x, acc.x), fmaf(s, a.y, acc.y),
                       fmaf(s, a.z, acc.z), fmaf(s, a.w, acc.w));
}

// ================== Weight fold: [embW; embb](129x128) @ W0 ================
__global__ __launch_bounds__(128) void fold_emb(
    const float* __restrict__ embW, const float* __restrict__ embb,
    const float* __restrict__ W0, float* __restrict__ W01,
    float* __restrict__ b01)
{
    const int r = blockIdx.x;   // 0..128; r==128 -> bias row
    const int c = threadIdx.x;
    __shared__ float rs[128];
    rs[c] = (r < 128) ? embW[r * 128 + c] : embb[c];
    __syncthreads();
    float s = 0.f;
#pragma unroll 8
    for (int k = 0; k < 128; k++) s = fmaf(rs[k], W0[k * 128 + c], s);
    if (r < 128) W01[r * 128 + c] = s;
    else         b01[c] = s;
}

// ============================ GEMM: [n,128] @ [128,128] =====================
// BM=128, full N=128, BK=32. 256 threads, 8x8 micro-tile. Grid = 512 blocks
// (2 blocks/CU). Register prefetch of next k-chunk.
// ASTRIDE=257: store bank=(4*a_kq + a_m)%32 -> uniform 2-way (free, m136);
// A-reads are 16-lane broadcasts (free).
// WSTRIDE=140 REQUIRED: swizzle c->c+4*(c>>5) reaches index 139; 132 made the
// flat map non-injective ((k,120+t) collided with (k+1,t)) -- round-4 bug.
// Epilogue: out = (acc + bias) * rowscale  (bias/rowscale nullable)
#define ASTRIDE 257
#define WSTRIDE 140
__global__ __launch_bounds__(256) void gemm128(
    const float* __restrict__ A, const float* __restrict__ W,
    const float* __restrict__ bias, const float* __restrict__ rowscale,
    float* __restrict__ out, int n)
{
    __shared__ float As[32 * ASTRIDE];  // [k][m] transposed
    __shared__ float Ws[32 * WSTRIDE];  // [k][c'] swizzled
    const int tid  = threadIdx.x;
    const int rb   = blockIdx.x * 128;
    const int tc   = tid & 15;
    const int tr   = tid >> 4;
    const int colg = tc * 8;
    const int cswz = colg + ((colg >> 5) << 2);
    const int rowg = tr * 8;

    // staging coords
    const int a_kq = tid & 7;    // float4 idx along k
    const int a_m  = tid >> 3;   // row 0..31 (+32*t)
    const int w_c  = (tid & 31) * 4;
    const int w_cs = w_c + ((w_c >> 5) << 2);
    const int w_k  = tid >> 5;   // k-row 0..7 (+8*t)

    float acc[8][8];
#pragma unroll
    for (int i = 0; i < 8; i++)
#pragma unroll
        for (int j = 0; j < 8; j++) acc[i][j] = 0.f;

    float4 areg[4], wreg[4];
#pragma unroll
    for (int t = 0; t < 4; t++)
        areg[t] = *(const float4*)&A[(size_t)(rb + t * 32 + a_m) * 128 + a_kq * 4];
#pragma unroll
    for (int t = 0; t < 4; t++)
        wreg[t] = *(const float4*)&W[(size_t)(t * 8 + w_k) * 128 + w_c];

#pragma unroll 1
    for (int k0 = 0; k0 < 128; k0 += 32) {
#pragma unroll
        for (int t = 0; t < 4; t++) {
            const int m = t * 32 + a_m;
            const float4 av = areg[t];
            As[(a_kq * 4 + 0) * ASTRIDE + m] = av.x;
            As[(a_kq * 4 + 1) * ASTRIDE + m] = av.y;
            As[(a_kq * 4 + 2) * ASTRIDE + m] = av.z;
            As[(a_kq * 4 + 3) * ASTRIDE + m] = av.w;
        }
#pragma unroll
        for (int t = 0; t < 4; t++)
            *(float4*)&Ws[(t * 8 + w_k) * WSTRIDE + w_cs] = wreg[t];
        __syncthreads();
        if (k0 < 96) {
#pragma unroll
            for (int t = 0; t < 4; t++)
                areg[t] = *(const float4*)&A[(size_t)(rb + t * 32 + a_m) * 128 + k0 + 32 + a_kq * 4];
#pragma unroll
            for (int t = 0; t < 4; t++)
                wreg[t] = *(const float4*)&W[(size_t)(k0 + 32 + t * 8 + w_k) * 128 + w_c];
        }
#pragma unroll 8
        for (int kk = 0; kk < 32; kk++) {
            float4 a0 = *(const float4*)&As[kk * ASTRIDE + rowg];
            float4 a1 = *(const float4*)&As[kk * ASTRIDE + rowg + 4];
            float4 b0 = *(const float4*)&Ws[kk * WSTRIDE + cswz];
            float4 b1 = *(const float4*)&Ws[kk * WSTRIDE + cswz + 4];
            float av[8] = {a0.x, a0.y, a0.z, a0.w, a1.x, a1.y, a1.z, a1.w};
            float bv[8] = {b0.x, b0.y, b0.z, b0.w, b1.x, b1.y, b1.z, b1.w};
#pragma unroll
            for (int i = 0; i < 8; i++)
#pragma unroll
                for (int j = 0; j < 8; j++) acc[i][j] = fmaf(av[i], bv[j], acc[i][j]);
        }
        __syncthreads();
    }

    float4 bb0 = make_float4(0.f, 0.f, 0.f, 0.f), bb1 = bb0;
    if (bias) {
        bb0 = *(const float4*)&bias[colg];
        bb1 = *(const float4*)&bias[colg + 4];
    }
#pragma unroll
    for (int i = 0; i < 8; i++) {
        const int row  = rb + rowg + i;
        const float sc = rowscale ? rowscale[row] : 1.f;
        float4 o0, o1;
        o0.x = (acc[i][0] + bb0.x) * sc;  o0.y = (acc[i][1] + bb0.y) * sc;
        o0.z = (acc[i][2] + bb0.z) * sc;  o0.w = (acc[i][3] + bb0.w) * sc;
        o1.x = (acc[i][4] + bb1.x) * sc;  o1.y = (acc[i][5] + bb1.y) * sc;
        o1.z = (acc[i][6] + bb1.z) * sc;  o1.w = (acc[i][7] + bb1.w) * sc;
        *(float4*)&out[(size_t)row * 128 + colg]     = o0;
        *(float4*)&out[(size_t)row * 128 + colg + 4] = o1;
    }
}

// ============================ Degree / CSR build ============================
__global__ void count_edges(const int* __restrict__ dst, int* __restrict__ cnt, int E)
{
    int e = blockIdx.x * blockDim.x + threadIdx.x;
    if (e < E) atomicAdd(&cnt[dst[e]], 1);
}

// scan1 also emits dinv = rsqrt(deg+1)
__global__ void scan1(const int* __restrict__ cnt, int* __restrict__ offs,
                      int* __restrict__ bsum, float* __restrict__ dinv)
{
    __shared__ int tmp[256];
    int t = threadIdx.x;
    int i = blockIdx.x * 256 + t;
    int v = cnt[i];
    dinv[i] = rsqrtf((float)(v + 1));
    tmp[t] = v;
    __syncthreads();
    for (int o = 1; o < 256; o <<= 1) {
        int add = (t >= o) ? tmp[t - o] : 0;
        __syncthreads();
        tmp[t] += add;
        __syncthreads();
    }
    offs[i] = tmp[t] - v;
    if (t == 255) bsum[blockIdx.x] = tmp[255];
}

__global__ void scan2(const int* __restrict__ bsum, int* __restrict__ boff)
{
    __shared__ int tmp[256];
    int t = threadIdx.x;
    int v = bsum[t];
    tmp[t] = v;
    __syncthreads();
    for (int o = 1; o < 256; o <<= 1) {
        int add = (t >= o) ? tmp[t - o] : 0;
        __syncthreads();
        tmp[t] += add;
        __syncthreads();
    }
    boff[t] = tmp[t] - v;
}

__global__ void scan3(int* __restrict__ offs, const int* __restrict__ boff,
                      int* __restrict__ cursor, int n, int E)
{
    int i = blockIdx.x * 256 + threadIdx.x;
    int v = offs[i] + boff[blockIdx.x];
    offs[i]   = v;
    cursor[i] = v;
    if (i == 0) offs[n] = E;
}

__global__ void scatter_edges(const int* __restrict__ src, const int* __restrict__ dst,
                              int* __restrict__ cursor, int* __restrict__ csr, int E)
{
    int e = blockIdx.x * blockDim.x + threadIdx.x;
    if (e < E) {
        int d   = dst[e];
        int pos = atomicAdd(&cursor[d], 1);
        csr[pos] = src[e];
    }
}

// ============================ Aggregation ===================================
// h_out[i] = relu((hs[i] + sum_{src in in(i)} hs[src]) * dinv[i] + b)
// 32 lanes/node (float4 per lane), 8 nodes per 256-thread block.
// All 16 candidate rows loaded into registers FIRST (scheduling fence keeps
// the 16 global_load_dwordx4 in flight together), then masked-FMA'd.
__global__ __launch_bounds__(256) void aggregate(
    const float* __restrict__ hs, const int* __restrict__ csr,
    const int* __restrict__ offs, const float* __restrict__ dinv,
    const float* __restrict__ bias, float* __restrict__ hout,
    const float* __restrict__ pool_p, float* __restrict__ scores, int n)
{
    const int grp  = threadIdx.x >> 5;
    const int lane = threadIdx.x & 31;
    const int node = blockIdx.x * 8 + grp;
    const float4* __restrict__ hv = (const float4*)hs;

    const int e0 = offs[node], e1 = offs[node + 1];

    int   ix[16];
    float mk[16];
#pragma unroll
    for (int j = 0; j < 16; j++) {
        const int  e  = e0 + j;
        const bool v  = e < e1;
        const int  ce = v ? e : (e1 > 0 ? e1 - 1 : 0);
        ix[j] = csr[ce];
        mk[j] = v ? 1.f : 0.f;
    }

    float4 self = hv[(size_t)node * 32 + lane];
    float4 r[16];
#pragma unroll
    for (int j = 0; j < 16; j++)
        r[j] = hv[(size_t)ix[j] * 32 + lane];
    asm volatile("" ::: "memory");  // keep all 16 loads in flight before use

    float4 a0 = self;
    float4 a1 = make_float4(0.f, 0.f, 0.f, 0.f);
    float4 a2 = a1, a3 = a1;
#pragma unroll
    for (int j = 0; j < 16; j += 4) {
        a0 = f4fma(mk[j + 0], r[j + 0], a0);
        a1 = f4fma(mk[j + 1], r[j + 1], a1);
        a2 = f4fma(mk[j + 2], r[j + 2], a2);
        a3 = f4fma(mk[j + 3], r[j + 3], a3);
    }
    for (int e = e0 + 16; e < e1; e++) {  // rare tail (deg > 16)
        a1 = f4add(a1, hv[(size_t)csr[e] * 32 + lane]);
    }

    float4 s = f4add(f4add(a0, a1), f4add(a2, a3));
    const float dv = dinv[node];
    const float4 bb = ((const float4*)bias)[lane];
    float4 o;
    o.x = fmaxf(fmaf(s.x, dv, bb.x), 0.f);
    o.y = fmaxf(fmaf(s.y, dv, bb.y), 0.f);
    o.z = fmaxf(fmaf(s.z, dv, bb.z), 0.f);
    o.w = fmaxf(fmaf(s.w, dv, bb.w), 0.f);
    ((float4*)hout)[(size_t)node * 32 + lane] = o;

    if (scores) {  // wave-uniform branch (fused pooling score)
        float4 pv = ((const float4*)pool_p)[lane];
        float d  = o.x * pv.x + o.y * pv.y + o.z * pv.z + o.w * pv.w;
        float nn = pv.x * pv.x + pv.y * pv.y + pv.z * pv.z + pv.w * pv.w;
#pragma unroll
        for (int off = 16; off > 0; off >>= 1) {
            d  += __shfl_xor(d, off);
            nn += __shfl_xor(nn, off);
        }
        if (lane == 0) scores[node] = d * rsqrtf(nn);
    }
}

// ============================ TopK pool (k=256 of 512) ======================
__global__ __launch_bounds__(512) void topk_pool(
    const float* __restrict__ scores, const float* __restrict__ h,
    float* __restrict__ pooled)
{
    __shared__ float s[512];
    __shared__ int   sel[256];
    __shared__ float w[256];
    __shared__ float4 red[512];
    const int g = blockIdx.x;
    const int i = threadIdx.x;
    s[i] = scores[g * 512 + i];
    __syncthreads();
    float si = s[i];
    int rank = 0;
    for (int j = 0; j < 512; j++) {
        float sj = s[j];
        rank += (sj > si) || (sj == si && j < i);
    }
    if (rank < 256) {
        sel[rank] = i;
        w[rank]   = tanhf(si) * (1.f / 256.f);
    }
    __syncthreads();
    const int c   = (i & 31) * 4;
    const int grp = i >> 5;
    float4 acc = make_float4(0.f, 0.f, 0.f, 0.f);
    for (int t = grp; t < 256; t += 16) {
        float wt  = w[t];
        int   idx = sel[t];
        float4 r = *(const float4*)&h[((size_t)g * 512 + idx) * 128 + c];
        acc = f4fma(wt, r, acc);
    }
    red[i] = acc;
    __syncthreads();
    if (i < 256) red[i] = f4add(red[i], red[i + 256]);
    __syncthreads();
    if (i < 128) red[i] = f4add(red[i], red[i + 128]);
    __syncthreads();
    if (i < 64) red[i] = f4add(red[i], red[i + 64]);
    __syncthreads();
    if (i < 32) {
        float4 v = f4add(red[i], red[i + 32]);
        *(float4*)&pooled[g * 128 + i * 4] = v;
    }
}

// ============================ MLP head ======================================
__global__ __launch_bounds__(128) void mlp_head(
    const float* __restrict__ pooled,
    const float* __restrict__ fc1W, const float* __restrict__ fc1b,
    const float* __restrict__ fc2W, const float* __restrict__ fc2b,
    const float* __restrict__ fc3W, const float* __restrict__ fc3b,
    float* __restrict__ out)
{
    __shared__ float pld[128];
    __shared__ float z1[128];
    __shared__ float z2[64];
    int g = blockIdx.x, j = threadIdx.x;
    pld[j] = pooled[g * 128 + j];
    __syncthreads();
    float a = fc1b[j];
    for (int k = 0; k < 128; k++) a += pld[k] * fc1W[k * 128 + j];
    z1[j] = fmaxf(a, 0.f);
    __syncthreads();
    if (j < 64) {
        float b = fc2b[j];
        for (int k = 0; k < 128; k++) b += z1[k] * fc2W[k * 64 + j];
        z2[j] = fmaxf(b, 0.f);
    }
    __syncthreads();
    if (j < 10) {
        float o = fc3b[j];
        for (int k = 0; k < 64; k++) o += z2[k] * fc3W[k * 10 + j];
        out[g * 10 + j] = o;
    }
}

// ============================ Launcher ======================================
extern "C" void kernel_launch(void* const* d_in, const int* in_sizes, int n_in,
                              void* d_out, int out_size, void* d_ws, size_t ws_size,
                              hipStream_t stream)
{
    const float* x     = (const float*)d_in[0];
    const int*   eidx  = (const int*)d_in[1];
    const float* embW  = (const float*)d_in[3];
    const float* embb  = (const float*)d_in[4];
    const float* gcnW  = (const float*)d_in[5];
    const float* gcnb  = (const float*)d_in[6];
    const float* poolp = (const float*)d_in[7];
    const float* fc1W  = (const float*)d_in[8];
    const float* fc1b  = (const float*)d_in[9];
    const float* fc2W  = (const float*)d_in[10];
    const float* fc2b  = (const float*)d_in[11];
    const float* fc3W  = (const float*)d_in[12];
    const float* fc3b  = (const float*)d_in[13];
    float* out = (float*)d_out;

    const int n = in_sizes[0] / 128;   // 65536
    const int E = in_sizes[1] / 2;     // 524288
    const int G = n / 512;             // 128

    const int* src = eidx;
    const int* dst = eidx + E;

    char* ws = (char*)d_ws;
    size_t off = 0;
    auto carve = [&](size_t bytes) {
        void* p = ws + off;
        off += (bytes + 255) & ~(size_t)255;
        return p;
    };
    float* h      = (float*)carve((size_t)n * 128 * 4);
    float* hs     = (float*)carve((size_t)n * 128 * 4);
    float* dinv   = (float*)carve((size_t)n * 4);
    int*   cnt    = (int*)carve((size_t)n * 4);
    int*   offs   = (int*)carve((size_t)(n + 1) * 4);
    int*   cursor = (int*)carve((size_t)n * 4);
    int*   bsum   = (int*)carve(256 * 4);
    int*   boff   = (int*)carve(256 * 4);
    int*   csr    = (int*)carve((size_t)E * 4);
    float* scores = (float*)carve((size_t)n * 4);
    float* pooled = (float*)carve((size_t)G * 128 * 4);
    float* W01    = (float*)carve(128 * 128 * 4);
    float* b01    = (float*)carve(128 * 4);
    (void)ws_size;

    // ---- degree + CSR build ----
    hipMemsetAsync(cnt, 0, (size_t)n * 4, stream);
    count_edges<<<E / 256, 256, 0, stream>>>(dst, cnt, E);
    scan1<<<n / 256, 256, 0, stream>>>(cnt, offs, bsum, dinv);
    scan2<<<1, 256, 0, stream>>>(bsum, boff);
    scan3<<<n / 256, 256, 0, stream>>>(offs, boff, cursor, n, E);
    scatter_edges<<<E / 256, 256, 0, stream>>>(src, dst, cursor, csr, E);

    // ---- embedding folded into layer-0 weight ----
    fold_emb<<<129, 128, 0, stream>>>(embW, embb, gcnW, W01, b01);

    // ---- layer 0 (folded) ----
    gemm128<<<n / 128, 256, 0, stream>>>(x, W01, b01, dinv, hs, n);
    aggregate<<<n / 8, 256, 0, stream>>>(hs, csr, offs, dinv, gcnb, h,
                                         poolp, nullptr, n);

    // ---- layers 1,2 (score fused into last aggregate) ----
    for (int l = 1; l < 3; l++) {
        gemm128<<<n / 128, 256, 0, stream>>>(h, gcnW + (size_t)l * 128 * 128,
                                             nullptr, dinv, hs, n);
        aggregate<<<n / 8, 256, 0, stream>>>(
            hs, csr, offs, dinv, gcnb + (size_t)l * 128, h,
            poolp, (l == 2) ? scores : nullptr, n);
    }

    // ---- topk pool + MLP ----
    topk_pool<<<G, 512, 0, stream>>>(scores, h, pooled);
    mlp_head<<<G, 128, 0, stream>>>(pooled, fc1W, fc1b, fc2W, fc2b, fc3W, fc3b, out);
}